// Round 1
// baseline (3777.378 us; speedup 1.0000x reference)
//
#include <hip/hip_runtime.h>

// ---------------------------------------------------------------------------
// GCN 3-layer forward.  N=50000, E=800000, D=H=128, C=40 (derived at runtime).
// Round 0: correctness baseline. Atomic-scatter aggregation; f32 everywhere.
// ws layout (floats): [dinv: N][bufA: N*128][bufB: N*128]  = ~51.4 MB
// ---------------------------------------------------------------------------

__global__ void k_deg_init(float* __restrict__ deg, int n) {
    int i = blockIdx.x * blockDim.x + threadIdx.x;
    if (i < n) deg[i] = 1.0f;   // self-loop
}

__global__ void k_deg_count(const int* __restrict__ ei, float* __restrict__ deg, int E) {
    int e = blockIdx.x * blockDim.x + threadIdx.x;
    if (e < E) atomicAdd(&deg[ei[E + e]], 1.0f);   // dst = ei[E+e]
}

__global__ void k_dinv(float* __restrict__ deg, int n) {
    int i = blockIdx.x * blockDim.x + threadIdx.x;
    if (i < n) deg[i] = rsqrtf(deg[i]);            // deg >= 1 always
}

// Y[N,F] = X[N,128] @ W[128,F].  W staged fully in LDS; each thread does 4 rows
// to amortize the LDS read of W over 4 FMAs.
template <int F>
__global__ void k_gemm(const float* __restrict__ X, const float* __restrict__ W,
                       float* __restrict__ Y, int nrb /* = N/4 */) {
    __shared__ float sW[128 * F];
    for (int i = threadIdx.x; i < 128 * F; i += blockDim.x) sW[i] = W[i];
    __syncthreads();
    int tid = blockIdx.x * blockDim.x + threadIdx.x;
    int total = nrb * F;
    if (tid >= total) return;
    int rb = tid / F;
    int c  = tid - rb * F;
    const float* x0 = X + (size_t)rb * 4 * 128;
    float a0 = 0.f, a1 = 0.f, a2 = 0.f, a3 = 0.f;
    for (int k = 0; k < 128; ++k) {
        float w = sW[k * F + c];
        a0 = fmaf(x0[k], w, a0);
        a1 = fmaf(x0[128 + k], w, a1);
        a2 = fmaf(x0[256 + k], w, a2);
        a3 = fmaf(x0[384 + k], w, a3);
    }
    float* y = Y + (size_t)rb * 4 * F + c;
    y[0]     = a0;
    y[F]     = a1;
    y[2 * F] = a2;
    y[3 * F] = a3;
}

// out[i,:] = dinv[i]^2 * XW[i,:]   (self-loop term; also zero-inits the buffer)
template <int F>
__global__ void k_self_init(const float* __restrict__ XW, const float* __restrict__ dinv,
                            float* __restrict__ out, int n) {
    constexpr int F4 = F / 4;
    int tid = blockIdx.x * blockDim.x + threadIdx.x;
    int total = n * F4;
    if (tid >= total) return;
    int r = tid / F4;
    float dv = dinv[r];
    float w = dv * dv;
    float4 v = ((const float4*)XW)[tid];
    float4 o;
    o.x = w * v.x; o.y = w * v.y; o.z = w * v.z; o.w = w * v.w;
    ((float4*)out)[tid] = o;
}

// out[dst,:] += dinv[src]*dinv[dst] * XW[src,:]  via f32 atomics
template <int F>
__global__ void k_agg_edges(const float* __restrict__ XW, const int* __restrict__ ei,
                            const float* __restrict__ dinv, float* __restrict__ out, int E) {
    constexpr int F4 = F / 4;
    long long idx = (long long)blockIdx.x * blockDim.x + threadIdx.x;
    long long total = (long long)E * F4;
    if (idx >= total) return;
    int e = (int)(idx / F4);
    int c = (int)(idx - (long long)e * F4);
    int s = ei[e];
    int d = ei[E + e];
    float w = dinv[s] * dinv[d];
    float4 v = ((const float4*)XW)[(size_t)s * F4 + c];
    float* o = out + (size_t)d * F + (size_t)c * 4;
    atomicAdd(o + 0, w * v.x);
    atomicAdd(o + 1, w * v.y);
    atomicAdd(o + 2, w * v.z);
    atomicAdd(o + 3, w * v.w);
}

template <int F, bool RELU>
__global__ void k_bias(float* __restrict__ out, const float* __restrict__ b, int n) {
    int tid = blockIdx.x * blockDim.x + threadIdx.x;
    int total = n * F;
    if (tid >= total) return;
    int c = tid % F;
    float v = out[tid] + b[c];
    out[tid] = RELU ? fmaxf(v, 0.0f) : v;
}

static inline int cdiv(long long a, int b) { return (int)((a + b - 1) / b); }

extern "C" void kernel_launch(void* const* d_in, const int* in_sizes, int n_in,
                              void* d_out, int out_size, void* d_ws, size_t ws_size,
                              hipStream_t stream) {
    const float* x  = (const float*)d_in[0];
    const int*   ei = (const int*)d_in[1];
    const float* W1 = (const float*)d_in[2];
    const float* b1 = (const float*)d_in[3];
    const float* W2 = (const float*)d_in[4];
    const float* b2 = (const float*)d_in[5];
    const float* W3 = (const float*)d_in[6];
    const float* b3 = (const float*)d_in[7];
    float* out = (float*)d_out;

    const int N = in_sizes[0] / 128;   // 50000
    const int E = in_sizes[1] / 2;     // 800000
    constexpr int H = 128;
    constexpr int C = 40;

    float* ws   = (float*)d_ws;
    float* dinv = ws;                       // N
    float* bufA = ws + N;                   // N*128  (XW scratch)
    float* bufB = bufA + (size_t)N * 128;   // N*128  (activations)

    const int BT = 256;
    const int nrb = N / 4;   // 12500

    // degrees -> dinv
    k_deg_init<<<cdiv(N, BT), BT, 0, stream>>>(dinv, N);
    k_deg_count<<<cdiv(E, BT), BT, 0, stream>>>(ei, dinv, E);
    k_dinv<<<cdiv(N, BT), BT, 0, stream>>>(dinv, N);

    // ---- layer 1: relu(agg(x @ W1) + b1) -> bufB
    k_gemm<H><<<cdiv((long long)nrb * H, BT), BT, 0, stream>>>(x, W1, bufA, nrb);
    k_self_init<H><<<cdiv((long long)N * (H / 4), BT), BT, 0, stream>>>(bufA, dinv, bufB, N);
    k_agg_edges<H><<<cdiv((long long)E * (H / 4), BT), BT, 0, stream>>>(bufA, ei, dinv, bufB, E);
    k_bias<H, true><<<cdiv((long long)N * H, BT), BT, 0, stream>>>(bufB, b1, N);

    // ---- layer 2: relu(agg(bufB @ W2) + b2) -> bufB
    k_gemm<H><<<cdiv((long long)nrb * H, BT), BT, 0, stream>>>(bufB, W2, bufA, nrb);
    k_self_init<H><<<cdiv((long long)N * (H / 4), BT), BT, 0, stream>>>(bufA, dinv, bufB, N);
    k_agg_edges<H><<<cdiv((long long)E * (H / 4), BT), BT, 0, stream>>>(bufA, ei, dinv, bufB, E);
    k_bias<H, true><<<cdiv((long long)N * H, BT), BT, 0, stream>>>(bufB, b2, N);

    // ---- layer 3: agg(bufB @ W3) + b3 -> d_out
    k_gemm<C><<<cdiv((long long)nrb * C, BT), BT, 0, stream>>>(bufB, W3, bufA, nrb);
    k_self_init<C><<<cdiv((long long)N * (C / 4), BT), BT, 0, stream>>>(bufA, dinv, out, N);
    k_agg_edges<C><<<cdiv((long long)E * (C / 4), BT), BT, 0, stream>>>(bufA, ei, dinv, out, E);
    k_bias<C, false><<<cdiv((long long)N * C, BT), BT, 0, stream>>>(out, b3, N);
}

// Round 2
// 946.290 us; speedup vs baseline: 3.9918x; 3.9918x over previous
//
#include <hip/hip_runtime.h>

// ---------------------------------------------------------------------------
// GCN 3-layer forward.  N=50000, E=800000, D=H=128, C=40.
// Round 2: CSR-by-dst + gather aggregation (no f32 atomics), fused bias/ReLU.
// ws layout: [deg:N int][rowptr:N+1 int][cursor:N int][dinv:N f32]
//            [csr:E int2 (src, w-bits)][bufA:N*128 f32][bufB:N*128 f32]
// ---------------------------------------------------------------------------

__global__ void k_deg_count(const int* __restrict__ ei, int* __restrict__ deg, int E) {
    int e = blockIdx.x * blockDim.x + threadIdx.x;
    if (e < E) atomicAdd(&deg[ei[E + e]], 1);   // dst = ei[E+e]
}

// Single-block exclusive scan: thread t owns a contiguous chunk; serial sum,
// block-scan of 1024 partials, serial re-walk.  ~200 KB of data; few µs.
__global__ void k_scan(const int* __restrict__ deg, int* __restrict__ rowptr,
                       int* __restrict__ cursor, int n) {
    __shared__ int ssum[1024];
    int t = threadIdx.x;
    int chunk = (n + 1023) >> 10;
    int beg = t * chunk;
    int end = min(beg + chunk, n);
    int s = 0;
    for (int i = beg; i < end; ++i) s += deg[i];
    ssum[t] = s;
    __syncthreads();
    for (int off = 1; off < 1024; off <<= 1) {
        int v = (t >= off) ? ssum[t - off] : 0;
        __syncthreads();
        ssum[t] += v;
        __syncthreads();
    }
    int run = ssum[t] - s;   // exclusive prefix of this thread's chunk
    for (int i = beg; i < end; ++i) {
        rowptr[i] = run;
        cursor[i] = run;
        run += deg[i];
    }
    if (t == 1023) rowptr[n] = ssum[1023];
}

__global__ void k_dinv(const int* __restrict__ deg, float* __restrict__ dinv, int n) {
    int i = blockIdx.x * blockDim.x + threadIdx.x;
    if (i < n) dinv[i] = rsqrtf((float)(deg[i] + 1));   // +1 self-loop
}

// csr[pos] = {src, bits(dinv[src]*dinv[dst])}
__global__ void k_fill(const int* __restrict__ ei, int* __restrict__ cursor,
                       const float* __restrict__ dinv, int2* __restrict__ csr, int E) {
    int e = blockIdx.x * blockDim.x + threadIdx.x;
    if (e >= E) return;
    int s = ei[e];
    int d = ei[E + e];
    int pos = atomicAdd(&cursor[d], 1);
    int2 p;
    p.x = s;
    p.y = __float_as_int(dinv[s] * dinv[d]);
    csr[pos] = p;
}

// Y[N,F] = X[N,128] @ W[128,F].  W staged fully in LDS; 4 rows/thread.
template <int F>
__global__ void k_gemm(const float* __restrict__ X, const float* __restrict__ W,
                       float* __restrict__ Y, int nrb) {
    __shared__ float sW[128 * F];
    for (int i = threadIdx.x; i < 128 * F; i += blockDim.x) sW[i] = W[i];
    __syncthreads();
    int tid = blockIdx.x * blockDim.x + threadIdx.x;
    int total = nrb * F;
    if (tid >= total) return;
    int rb = tid / F;
    int c  = tid - rb * F;
    const float* x0 = X + (size_t)rb * 4 * 128;
    float a0 = 0.f, a1 = 0.f, a2 = 0.f, a3 = 0.f;
    for (int k = 0; k < 128; ++k) {
        float w = sW[k * F + c];
        a0 = fmaf(x0[k], w, a0);
        a1 = fmaf(x0[128 + k], w, a1);
        a2 = fmaf(x0[256 + k], w, a2);
        a3 = fmaf(x0[384 + k], w, a3);
    }
    float* y = Y + (size_t)rb * 4 * F + c;
    y[0]     = a0;
    y[F]     = a1;
    y[2 * F] = a2;
    y[3 * F] = a3;
}

// One wave per dst node, F=128: lane holds float2 (2 cols).  Self-loop init,
// neighbor gather over CSR, fused bias (+ReLU), single coalesced write.
template <bool RELU>
__global__ void k_agg128(const float* __restrict__ XW, const int* __restrict__ rowptr,
                         const int2* __restrict__ csr, const float* __restrict__ dinv,
                         const float* __restrict__ bias, float* __restrict__ out, int n) {
    int wave = threadIdx.x >> 6;
    int lane = threadIdx.x & 63;
    int d = blockIdx.x * 4 + wave;
    if (d >= n) return;
    const float2* xw2 = (const float2*)XW;
    float dv = dinv[d];
    float2 v = xw2[(size_t)d * 64 + lane];
    float2 acc;
    acc.x = dv * dv * v.x;
    acc.y = dv * dv * v.y;
    int beg = rowptr[d], end = rowptr[d + 1];
    for (int j = beg; j < end; ++j) {
        int2 p = csr[j];                       // wave-uniform address (broadcast)
        float w = __int_as_float(p.y);
        float2 u = xw2[(size_t)p.x * 64 + lane];
        acc.x = fmaf(w, u.x, acc.x);
        acc.y = fmaf(w, u.y, acc.y);
    }
    float2 b = ((const float2*)bias)[lane];
    acc.x += b.x;
    acc.y += b.y;
    if (RELU) {
        acc.x = fmaxf(acc.x, 0.f);
        acc.y = fmaxf(acc.y, 0.f);
    }
    ((float2*)out)[(size_t)d * 64 + lane] = acc;
}

// One wave per dst node, F=40: lanes 0..39 hold one col each.
__global__ void k_agg40(const float* __restrict__ XW, const int* __restrict__ rowptr,
                        const int2* __restrict__ csr, const float* __restrict__ dinv,
                        const float* __restrict__ bias, float* __restrict__ out, int n) {
    int wave = threadIdx.x >> 6;
    int lane = threadIdx.x & 63;
    int d = blockIdx.x * 4 + wave;
    if (d >= n || lane >= 40) return;
    float dv = dinv[d];
    float acc = dv * dv * XW[(size_t)d * 40 + lane];
    int beg = rowptr[d], end = rowptr[d + 1];
    for (int j = beg; j < end; ++j) {
        int2 p = csr[j];
        acc = fmaf(__int_as_float(p.y), XW[(size_t)p.x * 40 + lane], acc);
    }
    out[(size_t)d * 40 + lane] = acc + bias[lane];
}

static inline int cdiv(long long a, int b) { return (int)((a + b - 1) / b); }

extern "C" void kernel_launch(void* const* d_in, const int* in_sizes, int n_in,
                              void* d_out, int out_size, void* d_ws, size_t ws_size,
                              hipStream_t stream) {
    const float* x  = (const float*)d_in[0];
    const int*   ei = (const int*)d_in[1];
    const float* W1 = (const float*)d_in[2];
    const float* b1 = (const float*)d_in[3];
    const float* W2 = (const float*)d_in[4];
    const float* b2 = (const float*)d_in[5];
    const float* W3 = (const float*)d_in[6];
    const float* b3 = (const float*)d_in[7];
    float* out = (float*)d_out;

    const int N = in_sizes[0] / 128;   // 50000
    const int E = in_sizes[1] / 2;     // 800000
    constexpr int H = 128;
    constexpr int C = 40;

    char* ws = (char*)d_ws;
    int*   deg    = (int*)ws;                 ws += (size_t)N * 4;
    int*   rowptr = (int*)ws;                 ws += (size_t)(N + 1) * 4;
    int*   cursor = (int*)ws;                 ws += (size_t)N * 4;
    float* dinv   = (float*)ws;               ws += (size_t)N * 4;
    ws = (char*)(((uintptr_t)ws + 15) & ~(uintptr_t)15);
    int2*  csr    = (int2*)ws;                ws += (size_t)E * 8;
    float* bufA   = (float*)ws;               ws += (size_t)N * 128 * 4;
    float* bufB   = (float*)ws;

    const int BT = 256;
    const int nrb = N / 4;

    // CSR build (per call; no state may survive)
    hipMemsetAsync(deg, 0, (size_t)N * 4, stream);
    k_deg_count<<<cdiv(E, BT), BT, 0, stream>>>(ei, deg, E);
    k_scan<<<1, 1024, 0, stream>>>(deg, rowptr, cursor, N);
    k_dinv<<<cdiv(N, BT), BT, 0, stream>>>(deg, dinv, N);
    k_fill<<<cdiv(E, BT), BT, 0, stream>>>(ei, cursor, dinv, csr, E);

    // layer 1
    k_gemm<H><<<cdiv((long long)nrb * H, BT), BT, 0, stream>>>(x, W1, bufA, nrb);
    k_agg128<true><<<cdiv(N, 4), BT, 0, stream>>>(bufA, rowptr, csr, dinv, b1, bufB, N);
    // layer 2
    k_gemm<H><<<cdiv((long long)nrb * H, BT), BT, 0, stream>>>(bufB, W2, bufA, nrb);
    k_agg128<true><<<cdiv(N, 4), BT, 0, stream>>>(bufA, rowptr, csr, dinv, b2, bufB, N);
    // layer 3
    k_gemm<C><<<cdiv((long long)nrb * C, BT), BT, 0, stream>>>(bufB, W3, bufA, nrb);
    k_agg40<<<cdiv(N, 4), BT, 0, stream>>>(bufA, rowptr, csr, dinv, b3, out, N);
}

// Round 3
// 599.539 us; speedup vs baseline: 6.3005x; 1.5784x over previous
//
#include <hip/hip_runtime.h>

// ---------------------------------------------------------------------------
// GCN 3-layer forward.  N=50000, E=800000, D=H=128, C=40.
// Round 3: LDS-tiled register-microtile f32 GEMMs (BM=64/BK=32, 4x8 per
// thread for F=128; BM=128, 4x5 for F=40).  CSR gather agg unchanged.
// ws layout: [deg:N int][rowptr:N+1 int][cursor:N int][dinv:N f32]
//            [csr:E int2 (src, w-bits)][bufA:N*128 f32][bufB:N*128 f32]
// ---------------------------------------------------------------------------

__global__ void k_deg_count(const int* __restrict__ ei, int* __restrict__ deg, int E) {
    int e = blockIdx.x * blockDim.x + threadIdx.x;
    if (e < E) atomicAdd(&deg[ei[E + e]], 1);   // dst = ei[E+e]
}

__global__ void k_scan(const int* __restrict__ deg, int* __restrict__ rowptr,
                       int* __restrict__ cursor, int n) {
    __shared__ int ssum[1024];
    int t = threadIdx.x;
    int chunk = (n + 1023) >> 10;
    int beg = t * chunk;
    int end = min(beg + chunk, n);
    int s = 0;
    for (int i = beg; i < end; ++i) s += deg[i];
    ssum[t] = s;
    __syncthreads();
    for (int off = 1; off < 1024; off <<= 1) {
        int v = (t >= off) ? ssum[t - off] : 0;
        __syncthreads();
        ssum[t] += v;
        __syncthreads();
    }
    int run = ssum[t] - s;
    for (int i = beg; i < end; ++i) {
        rowptr[i] = run;
        cursor[i] = run;
        run += deg[i];
    }
    if (t == 1023) rowptr[n] = ssum[1023];
}

__global__ void k_dinv(const int* __restrict__ deg, float* __restrict__ dinv, int n) {
    int i = blockIdx.x * blockDim.x + threadIdx.x;
    if (i < n) dinv[i] = rsqrtf((float)(deg[i] + 1));   // +1 self-loop
}

__global__ void k_fill(const int* __restrict__ ei, int* __restrict__ cursor,
                       const float* __restrict__ dinv, int2* __restrict__ csr, int E) {
    int e = blockIdx.x * blockDim.x + threadIdx.x;
    if (e >= E) return;
    int s = ei[e];
    int d = ei[E + e];
    int pos = atomicAdd(&cursor[d], 1);
    int2 p;
    p.x = s;
    p.y = __float_as_int(dinv[s] * dinv[d]);
    csr[pos] = p;
}

// ---- Y[N,128] = X[N,128] @ W[128,128].  BM=64, BK=32; 4x8 microtile. ----
__global__ __launch_bounds__(256) void k_gemm128(const float* __restrict__ X,
                                                 const float* __restrict__ W,
                                                 float* __restrict__ Y, int N) {
    __shared__ float sX[32][68];    // [k][m] transposed; 68*4=272 B row, 16B-aligned
    __shared__ float sW[32][128];   // [k][n]
    const int tid = threadIdx.x;
    const int bm = blockIdx.x * 64;
    const int m0 = (tid >> 4) * 4;  // 0..60
    const int n0 = (tid & 15) * 8;  // 0..120
    const int xr = tid >> 3;        // 0..31
    const int xf = tid & 7;         // 0..7
    float acc[4][8] = {};
    for (int k0 = 0; k0 < 128; k0 += 32) {
        #pragma unroll
        for (int rr = 0; rr < 2; ++rr) {
            int row = bm + xr + rr * 32;
            int rc = min(row, N - 1);
            float4 v = *(const float4*)(X + (size_t)rc * 128 + k0 + xf * 4);
            int m = xr + rr * 32;
            sX[xf * 4 + 0][m] = v.x;
            sX[xf * 4 + 1][m] = v.y;
            sX[xf * 4 + 2][m] = v.z;
            sX[xf * 4 + 3][m] = v.w;
        }
        #pragma unroll
        for (int it = 0; it < 4; ++it) {
            int i = tid + it * 256;
            int wr = i >> 5;
            int wf = i & 31;
            *(float4*)(&sW[wr][wf * 4]) =
                *(const float4*)(W + (size_t)(k0 + wr) * 128 + wf * 4);
        }
        __syncthreads();
        #pragma unroll
        for (int kk = 0; kk < 32; ++kk) {
            float4 a  = *(const float4*)(&sX[kk][m0]);
            float4 b0 = *(const float4*)(&sW[kk][n0]);
            float4 b1 = *(const float4*)(&sW[kk][n0 + 4]);
            float av[4] = {a.x, a.y, a.z, a.w};
            float bv[8] = {b0.x, b0.y, b0.z, b0.w, b1.x, b1.y, b1.z, b1.w};
            #pragma unroll
            for (int r = 0; r < 4; ++r)
                #pragma unroll
                for (int c = 0; c < 8; ++c)
                    acc[r][c] = fmaf(av[r], bv[c], acc[r][c]);
        }
        __syncthreads();
    }
    #pragma unroll
    for (int r = 0; r < 4; ++r) {
        int row = bm + m0 + r;
        if (row < N) {
            float4 o0 = {acc[r][0], acc[r][1], acc[r][2], acc[r][3]};
            float4 o1 = {acc[r][4], acc[r][5], acc[r][6], acc[r][7]};
            *(float4*)(Y + (size_t)row * 128 + n0)     = o0;
            *(float4*)(Y + (size_t)row * 128 + n0 + 4) = o1;
        }
    }
}

// ---- Y[N,40] = X[N,128] @ W[128,40].  BM=128, BK=32; 4x5 microtile. ----
__global__ __launch_bounds__(256) void k_gemm40(const float* __restrict__ X,
                                                const float* __restrict__ W,
                                                float* __restrict__ Y, int N) {
    __shared__ float sX[32][132];   // [k][m]; 132*4=528 B, 16B-aligned
    __shared__ float sW[32][40];
    const int tid = threadIdx.x;
    const int bm = blockIdx.x * 128;
    const int m0 = (tid >> 3) * 4;  // 0..124
    const int n0 = (tid & 7) * 5;   // 0..35
    const int xf = tid & 7;
    float acc[4][5] = {};
    for (int k0 = 0; k0 < 128; k0 += 32) {
        #pragma unroll
        for (int it = 0; it < 4; ++it) {
            int i = tid + it * 256;
            int row = bm + (i >> 3);
            int rc = min(row, N - 1);
            float4 v = *(const float4*)(X + (size_t)rc * 128 + k0 + xf * 4);
            int m = i >> 3;
            sX[xf * 4 + 0][m] = v.x;
            sX[xf * 4 + 1][m] = v.y;
            sX[xf * 4 + 2][m] = v.z;
            sX[xf * 4 + 3][m] = v.w;
        }
        // W tile: 32 rows x 40 cols = 320 float4
        for (int i = tid; i < 320; i += 256) {
            int wr = i / 10;
            int wf = i - wr * 10;
            *(float4*)(&sW[wr][wf * 4]) =
                *(const float4*)(W + (size_t)(k0 + wr) * 40 + wf * 4);
        }
        __syncthreads();
        #pragma unroll
        for (int kk = 0; kk < 32; ++kk) {
            float4 a = *(const float4*)(&sX[kk][m0]);
            float av[4] = {a.x, a.y, a.z, a.w};
            #pragma unroll
            for (int c = 0; c < 5; ++c) {
                float b = sW[kk][n0 + c];
                #pragma unroll
                for (int r = 0; r < 4; ++r)
                    acc[r][c] = fmaf(av[r], b, acc[r][c]);
            }
        }
        __syncthreads();
    }
    #pragma unroll
    for (int r = 0; r < 4; ++r) {
        int row = bm + m0 + r;
        if (row < N) {
            #pragma unroll
            for (int c = 0; c < 5; ++c)
                Y[(size_t)row * 40 + n0 + c] = acc[r][c];
        }
    }
}

// One wave per dst node, F=128: lane holds float2 (2 cols).
template <bool RELU>
__global__ void k_agg128(const float* __restrict__ XW, const int* __restrict__ rowptr,
                         const int2* __restrict__ csr, const float* __restrict__ dinv,
                         const float* __restrict__ bias, float* __restrict__ out, int n) {
    int wave = threadIdx.x >> 6;
    int lane = threadIdx.x & 63;
    int d = blockIdx.x * 4 + wave;
    if (d >= n) return;
    const float2* xw2 = (const float2*)XW;
    float dv = dinv[d];
    float2 v = xw2[(size_t)d * 64 + lane];
    float2 acc;
    acc.x = dv * dv * v.x;
    acc.y = dv * dv * v.y;
    int beg = rowptr[d], end = rowptr[d + 1];
    for (int j = beg; j < end; ++j) {
        int2 p = csr[j];
        float w = __int_as_float(p.y);
        float2 u = xw2[(size_t)p.x * 64 + lane];
        acc.x = fmaf(w, u.x, acc.x);
        acc.y = fmaf(w, u.y, acc.y);
    }
    float2 b = ((const float2*)bias)[lane];
    acc.x += b.x;
    acc.y += b.y;
    if (RELU) {
        acc.x = fmaxf(acc.x, 0.f);
        acc.y = fmaxf(acc.y, 0.f);
    }
    ((float2*)out)[(size_t)d * 64 + lane] = acc;
}

__global__ void k_agg40(const float* __restrict__ XW, const int* __restrict__ rowptr,
                        const int2* __restrict__ csr, const float* __restrict__ dinv,
                        const float* __restrict__ bias, float* __restrict__ out, int n) {
    int wave = threadIdx.x >> 6;
    int lane = threadIdx.x & 63;
    int d = blockIdx.x * 4 + wave;
    if (d >= n || lane >= 40) return;
    float dv = dinv[d];
    float acc = dv * dv * XW[(size_t)d * 40 + lane];
    int beg = rowptr[d], end = rowptr[d + 1];
    for (int j = beg; j < end; ++j) {
        int2 p = csr[j];
        acc = fmaf(__int_as_float(p.y), XW[(size_t)p.x * 40 + lane], acc);
    }
    out[(size_t)d * 40 + lane] = acc + bias[lane];
}

static inline int cdiv(long long a, int b) { return (int)((a + b - 1) / b); }

extern "C" void kernel_launch(void* const* d_in, const int* in_sizes, int n_in,
                              void* d_out, int out_size, void* d_ws, size_t ws_size,
                              hipStream_t stream) {
    const float* x  = (const float*)d_in[0];
    const int*   ei = (const int*)d_in[1];
    const float* W1 = (const float*)d_in[2];
    const float* b1 = (const float*)d_in[3];
    const float* W2 = (const float*)d_in[4];
    const float* b2 = (const float*)d_in[5];
    const float* W3 = (const float*)d_in[6];
    const float* b3 = (const float*)d_in[7];
    float* out = (float*)d_out;

    const int N = in_sizes[0] / 128;   // 50000
    const int E = in_sizes[1] / 2;     // 800000

    char* ws = (char*)d_ws;
    int*   deg    = (int*)ws;                 ws += (size_t)N * 4;
    int*   rowptr = (int*)ws;                 ws += (size_t)(N + 1) * 4;
    int*   cursor = (int*)ws;                 ws += (size_t)N * 4;
    float* dinv   = (float*)ws;               ws += (size_t)N * 4;
    ws = (char*)(((uintptr_t)ws + 15) & ~(uintptr_t)15);
    int2*  csr    = (int2*)ws;                ws += (size_t)E * 8;
    float* bufA   = (float*)ws;               ws += (size_t)N * 128 * 4;
    float* bufB   = (float*)ws;

    const int BT = 256;

    // CSR build (per call; no state survives between calls)
    hipMemsetAsync(deg, 0, (size_t)N * 4, stream);
    k_deg_count<<<cdiv(E, BT), BT, 0, stream>>>(ei, deg, E);
    k_scan<<<1, 1024, 0, stream>>>(deg, rowptr, cursor, N);
    k_dinv<<<cdiv(N, BT), BT, 0, stream>>>(deg, dinv, N);
    k_fill<<<cdiv(E, BT), BT, 0, stream>>>(ei, cursor, dinv, csr, E);

    // layer 1
    k_gemm128<<<cdiv(N, 64), 256, 0, stream>>>(x, W1, bufA, N);
    k_agg128<true><<<cdiv(N, 4), BT, 0, stream>>>(bufA, rowptr, csr, dinv, b1, bufB, N);
    // layer 2
    k_gemm128<<<cdiv(N, 64), 256, 0, stream>>>(bufB, W2, bufA, N);
    k_agg128<true><<<cdiv(N, 4), BT, 0, stream>>>(bufA, rowptr, csr, dinv, b2, bufB, N);
    // layer 3
    k_gemm40<<<cdiv(N, 128), 256, 0, stream>>>(bufB, W3, bufA, N);
    k_agg40<<<cdiv(N, 4), BT, 0, stream>>>(bufA, rowptr, csr, dinv, b3, out, N);
}

// Round 4
// 497.991 us; speedup vs baseline: 7.5852x; 1.2039x over previous
//
#include <hip/hip_runtime.h>

// ---------------------------------------------------------------------------
// GCN 3-layer forward.  N=50000, E=800000, D=H=128, C=40.
// Round 4: replace single-block k_scan (110 us, one CU) with a 3-phase
// device-wide scan (bsum -> bscan -> rowptr+dinv).  GEMM/agg unchanged.
// ws layout: [deg:N int][rowptr:N+1 int][cursor:N int][dinv:N f32][bsum:1024 int]
//            [csr:E int2 (src, w-bits)][bufA:N*128 f32][bufB:N*128 f32]
// ---------------------------------------------------------------------------

__global__ void k_deg_count(const int* __restrict__ ei, int* __restrict__ deg, int E) {
    int e = blockIdx.x * blockDim.x + threadIdx.x;
    if (e < E) atomicAdd(&deg[ei[E + e]], 1);   // dst = ei[E+e]
}

// Phase 1: bsum[b] = sum of deg[b*256 .. b*256+255]
__global__ void k_bsum(const int* __restrict__ deg, int* __restrict__ bsum, int n) {
    __shared__ int s[256];
    int t = threadIdx.x;
    int i = blockIdx.x * 256 + t;
    s[t] = (i < n) ? deg[i] : 0;
    __syncthreads();
    for (int off = 128; off > 0; off >>= 1) {
        if (t < off) s[t] += s[t + off];
        __syncthreads();
    }
    if (t == 0) bsum[blockIdx.x] = s[0];
}

// Phase 2: exclusive scan of nb (<=1024) block sums in one block; total -> *tot
__global__ void k_bscan(int* __restrict__ bsum, int* __restrict__ tot, int nb) {
    __shared__ int s[1024];
    int t = threadIdx.x;
    int v = (t < nb) ? bsum[t] : 0;
    s[t] = v;
    __syncthreads();
    for (int off = 1; off < 1024; off <<= 1) {
        int u = (t >= off) ? s[t - off] : 0;
        __syncthreads();
        s[t] += u;
        __syncthreads();
    }
    if (t < nb) bsum[t] = s[t] - v;        // exclusive prefix
    if (t == nb - 1) tot[0] = s[t];        // rowptr[N]
}

// Phase 3: rowptr/cursor = bsum[blk] + in-block exclusive scan; dinv fused.
__global__ void k_rowptr(const int* __restrict__ deg, const int* __restrict__ bsum,
                         int* __restrict__ rowptr, int* __restrict__ cursor,
                         float* __restrict__ dinv, int n) {
    __shared__ int s[256];
    int t = threadIdx.x;
    int i = blockIdx.x * 256 + t;
    int v = (i < n) ? deg[i] : 0;
    s[t] = v;
    __syncthreads();
    for (int off = 1; off < 256; off <<= 1) {
        int u = (t >= off) ? s[t - off] : 0;
        __syncthreads();
        s[t] += u;
        __syncthreads();
    }
    if (i < n) {
        int ex = bsum[blockIdx.x] + s[t] - v;
        rowptr[i] = ex;
        cursor[i] = ex;
        dinv[i] = rsqrtf((float)(v + 1));   // +1 self-loop
    }
}

__global__ void k_fill(const int* __restrict__ ei, int* __restrict__ cursor,
                       const float* __restrict__ dinv, int2* __restrict__ csr, int E) {
    int e = blockIdx.x * blockDim.x + threadIdx.x;
    if (e >= E) return;
    int s = ei[e];
    int d = ei[E + e];
    int pos = atomicAdd(&cursor[d], 1);
    int2 p;
    p.x = s;
    p.y = __float_as_int(dinv[s] * dinv[d]);
    csr[pos] = p;
}

// ---- Y[N,128] = X[N,128] @ W[128,128].  BM=64, BK=32; 4x8 microtile. ----
__global__ __launch_bounds__(256) void k_gemm128(const float* __restrict__ X,
                                                 const float* __restrict__ W,
                                                 float* __restrict__ Y, int N) {
    __shared__ float sX[32][68];
    __shared__ float sW[32][128];
    const int tid = threadIdx.x;
    const int bm = blockIdx.x * 64;
    const int m0 = (tid >> 4) * 4;
    const int n0 = (tid & 15) * 8;
    const int xr = tid >> 3;
    const int xf = tid & 7;
    float acc[4][8] = {};
    for (int k0 = 0; k0 < 128; k0 += 32) {
        #pragma unroll
        for (int rr = 0; rr < 2; ++rr) {
            int row = bm + xr + rr * 32;
            int rc = min(row, N - 1);
            float4 v = *(const float4*)(X + (size_t)rc * 128 + k0 + xf * 4);
            int m = xr + rr * 32;
            sX[xf * 4 + 0][m] = v.x;
            sX[xf * 4 + 1][m] = v.y;
            sX[xf * 4 + 2][m] = v.z;
            sX[xf * 4 + 3][m] = v.w;
        }
        #pragma unroll
        for (int it = 0; it < 4; ++it) {
            int i = tid + it * 256;
            int wr = i >> 5;
            int wf = i & 31;
            *(float4*)(&sW[wr][wf * 4]) =
                *(const float4*)(W + (size_t)(k0 + wr) * 128 + wf * 4);
        }
        __syncthreads();
        #pragma unroll
        for (int kk = 0; kk < 32; ++kk) {
            float4 a  = *(const float4*)(&sX[kk][m0]);
            float4 b0 = *(const float4*)(&sW[kk][n0]);
            float4 b1 = *(const float4*)(&sW[kk][n0 + 4]);
            float av[4] = {a.x, a.y, a.z, a.w};
            float bv[8] = {b0.x, b0.y, b0.z, b0.w, b1.x, b1.y, b1.z, b1.w};
            #pragma unroll
            for (int r = 0; r < 4; ++r)
                #pragma unroll
                for (int c = 0; c < 8; ++c)
                    acc[r][c] = fmaf(av[r], bv[c], acc[r][c]);
        }
        __syncthreads();
    }
    #pragma unroll
    for (int r = 0; r < 4; ++r) {
        int row = bm + m0 + r;
        if (row < N) {
            float4 o0 = {acc[r][0], acc[r][1], acc[r][2], acc[r][3]};
            float4 o1 = {acc[r][4], acc[r][5], acc[r][6], acc[r][7]};
            *(float4*)(Y + (size_t)row * 128 + n0)     = o0;
            *(float4*)(Y + (size_t)row * 128 + n0 + 4) = o1;
        }
    }
}

// ---- Y[N,40] = X[N,128] @ W[128,40].  BM=128, BK=32; 4x5 microtile. ----
__global__ __launch_bounds__(256) void k_gemm40(const float* __restrict__ X,
                                                const float* __restrict__ W,
                                                float* __restrict__ Y, int N) {
    __shared__ float sX[32][132];
    __shared__ float sW[32][40];
    const int tid = threadIdx.x;
    const int bm = blockIdx.x * 128;
    const int m0 = (tid >> 3) * 4;
    const int n0 = (tid & 7) * 5;
    const int xf = tid & 7;
    float acc[4][5] = {};
    for (int k0 = 0; k0 < 128; k0 += 32) {
        #pragma unroll
        for (int it = 0; it < 4; ++it) {
            int i = tid + it * 256;
            int row = bm + (i >> 3);
            int rc = min(row, N - 1);
            float4 v = *(const float4*)(X + (size_t)rc * 128 + k0 + xf * 4);
            int m = i >> 3;
            sX[xf * 4 + 0][m] = v.x;
            sX[xf * 4 + 1][m] = v.y;
            sX[xf * 4 + 2][m] = v.z;
            sX[xf * 4 + 3][m] = v.w;
        }
        for (int i = tid; i < 320; i += 256) {
            int wr = i / 10;
            int wf = i - wr * 10;
            *(float4*)(&sW[wr][wf * 4]) =
                *(const float4*)(W + (size_t)(k0 + wr) * 40 + wf * 4);
        }
        __syncthreads();
        #pragma unroll
        for (int kk = 0; kk < 32; ++kk) {
            float4 a = *(const float4*)(&sX[kk][m0]);
            float av[4] = {a.x, a.y, a.z, a.w};
            #pragma unroll
            for (int c = 0; c < 5; ++c) {
                float b = sW[kk][n0 + c];
                #pragma unroll
                for (int r = 0; r < 4; ++r)
                    acc[r][c] = fmaf(av[r], b, acc[r][c]);
            }
        }
        __syncthreads();
    }
    #pragma unroll
    for (int r = 0; r < 4; ++r) {
        int row = bm + m0 + r;
        if (row < N) {
            #pragma unroll
            for (int c = 0; c < 5; ++c)
                Y[(size_t)row * 40 + n0 + c] = acc[r][c];
        }
    }
}

// One wave per dst node, F=128: lane holds float2 (2 cols).
template <bool RELU>
__global__ void k_agg128(const float* __restrict__ XW, const int* __restrict__ rowptr,
                         const int2* __restrict__ csr, const float* __restrict__ dinv,
                         const float* __restrict__ bias, float* __restrict__ out, int n) {
    int wave = threadIdx.x >> 6;
    int lane = threadIdx.x & 63;
    int d = blockIdx.x * 4 + wave;
    if (d >= n) return;
    const float2* xw2 = (const float2*)XW;
    float dv = dinv[d];
    float2 v = xw2[(size_t)d * 64 + lane];
    float2 acc;
    acc.x = dv * dv * v.x;
    acc.y = dv * dv * v.y;
    int beg = rowptr[d], end = rowptr[d + 1];
    for (int j = beg; j < end; ++j) {
        int2 p = csr[j];
        float w = __int_as_float(p.y);
        float2 u = xw2[(size_t)p.x * 64 + lane];
        acc.x = fmaf(w, u.x, acc.x);
        acc.y = fmaf(w, u.y, acc.y);
    }
    float2 b = ((const float2*)bias)[lane];
    acc.x += b.x;
    acc.y += b.y;
    if (RELU) {
        acc.x = fmaxf(acc.x, 0.f);
        acc.y = fmaxf(acc.y, 0.f);
    }
    ((float2*)out)[(size_t)d * 64 + lane] = acc;
}

__global__ void k_agg40(const float* __restrict__ XW, const int* __restrict__ rowptr,
                        const int2* __restrict__ csr, const float* __restrict__ dinv,
                        const float* __restrict__ bias, float* __restrict__ out, int n) {
    int wave = threadIdx.x >> 6;
    int lane = threadIdx.x & 63;
    int d = blockIdx.x * 4 + wave;
    if (d >= n || lane >= 40) return;
    float dv = dinv[d];
    float acc = dv * dv * XW[(size_t)d * 40 + lane];
    int beg = rowptr[d], end = rowptr[d + 1];
    for (int j = beg; j < end; ++j) {
        int2 p = csr[j];
        acc = fmaf(__int_as_float(p.y), XW[(size_t)p.x * 40 + lane], acc);
    }
    out[(size_t)d * 40 + lane] = acc + bias[lane];
}

static inline int cdiv(long long a, int b) { return (int)((a + b - 1) / b); }

extern "C" void kernel_launch(void* const* d_in, const int* in_sizes, int n_in,
                              void* d_out, int out_size, void* d_ws, size_t ws_size,
                              hipStream_t stream) {
    const float* x  = (const float*)d_in[0];
    const int*   ei = (const int*)d_in[1];
    const float* W1 = (const float*)d_in[2];
    const float* b1 = (const float*)d_in[3];
    const float* W2 = (const float*)d_in[4];
    const float* b2 = (const float*)d_in[5];
    const float* W3 = (const float*)d_in[6];
    const float* b3 = (const float*)d_in[7];
    float* out = (float*)d_out;

    const int N = in_sizes[0] / 128;   // 50000
    const int E = in_sizes[1] / 2;     // 800000

    char* ws = (char*)d_ws;
    int*   deg    = (int*)ws;                 ws += (size_t)N * 4;
    int*   rowptr = (int*)ws;                 ws += (size_t)(N + 1) * 4;
    int*   cursor = (int*)ws;                 ws += (size_t)N * 4;
    float* dinv   = (float*)ws;               ws += (size_t)N * 4;
    int*   bsum   = (int*)ws;                 ws += (size_t)1024 * 4;
    ws = (char*)(((uintptr_t)ws + 15) & ~(uintptr_t)15);
    int2*  csr    = (int2*)ws;                ws += (size_t)E * 8;
    float* bufA   = (float*)ws;               ws += (size_t)N * 128 * 4;
    float* bufB   = (float*)ws;

    const int BT = 256;
    const int nb = cdiv(N, 256);   // 196 blocks (<=1024 required by k_bscan)

    // CSR build (per call; no state survives between calls)
    hipMemsetAsync(deg, 0, (size_t)N * 4, stream);
    k_deg_count<<<cdiv(E, BT), BT, 0, stream>>>(ei, deg, E);
    k_bsum<<<nb, 256, 0, stream>>>(deg, bsum, N);
    k_bscan<<<1, 1024, 0, stream>>>(bsum, rowptr + N, nb);
    k_rowptr<<<nb, 256, 0, stream>>>(deg, bsum, rowptr, cursor, dinv, N);
    k_fill<<<cdiv(E, BT), BT, 0, stream>>>(ei, cursor, dinv, csr, E);

    // layer 1
    k_gemm128<<<cdiv(N, 64), 256, 0, stream>>>(x, W1, bufA, N);
    k_agg128<true><<<cdiv(N, 4), BT, 0, stream>>>(bufA, rowptr, csr, dinv, b1, bufB, N);
    // layer 2
    k_gemm128<<<cdiv(N, 64), 256, 0, stream>>>(bufB, W2, bufA, N);
    k_agg128<true><<<cdiv(N, 4), BT, 0, stream>>>(bufA, rowptr, csr, dinv, b2, bufB, N);
    // layer 3
    k_gemm40<<<cdiv(N, 128), 256, 0, stream>>>(bufB, W3, bufA, N);
    k_agg40<<<cdiv(N, 4), BT, 0, stream>>>(bufA, rowptr, csr, dinv, b3, out, N);
}

// Round 5
// 416.108 us; speedup vs baseline: 9.0779x; 1.1968x over previous
//
#include <hip/hip_runtime.h>

// ---------------------------------------------------------------------------
// GCN 3-layer forward.  N=50000, E=800000, D=H=128, C=40.
// Round 5: unroll edge-gather loops (8x in agg128, 4x in agg40) for
// memory-level parallelism.  Round-4 profile: agg128 at 92 us was
// latency-bound (VALUBusy 13%, VGPR_Count 8 -> ~1 load in flight).
// FP accumulation order unchanged -> bitwise-identical results.
// ws layout: [deg:N int][rowptr:N+1 int][cursor:N int][dinv:N f32][bsum:1024 int]
//            [csr:E int2 (src, w-bits)][bufA:N*128 f32][bufB:N*128 f32]
// ---------------------------------------------------------------------------

__global__ void k_deg_count(const int* __restrict__ ei, int* __restrict__ deg, int E) {
    int e = blockIdx.x * blockDim.x + threadIdx.x;
    if (e < E) atomicAdd(&deg[ei[E + e]], 1);   // dst = ei[E+e]
}

__global__ void k_bsum(const int* __restrict__ deg, int* __restrict__ bsum, int n) {
    __shared__ int s[256];
    int t = threadIdx.x;
    int i = blockIdx.x * 256 + t;
    s[t] = (i < n) ? deg[i] : 0;
    __syncthreads();
    for (int off = 128; off > 0; off >>= 1) {
        if (t < off) s[t] += s[t + off];
        __syncthreads();
    }
    if (t == 0) bsum[blockIdx.x] = s[0];
}

__global__ void k_bscan(int* __restrict__ bsum, int* __restrict__ tot, int nb) {
    __shared__ int s[1024];
    int t = threadIdx.x;
    int v = (t < nb) ? bsum[t] : 0;
    s[t] = v;
    __syncthreads();
    for (int off = 1; off < 1024; off <<= 1) {
        int u = (t >= off) ? s[t - off] : 0;
        __syncthreads();
        s[t] += u;
        __syncthreads();
    }
    if (t < nb) bsum[t] = s[t] - v;
    if (t == nb - 1) tot[0] = s[t];
}

__global__ void k_rowptr(const int* __restrict__ deg, const int* __restrict__ bsum,
                         int* __restrict__ rowptr, int* __restrict__ cursor,
                         float* __restrict__ dinv, int n) {
    __shared__ int s[256];
    int t = threadIdx.x;
    int i = blockIdx.x * 256 + t;
    int v = (i < n) ? deg[i] : 0;
    s[t] = v;
    __syncthreads();
    for (int off = 1; off < 256; off <<= 1) {
        int u = (t >= off) ? s[t - off] : 0;
        __syncthreads();
        s[t] += u;
        __syncthreads();
    }
    if (i < n) {
        int ex = bsum[blockIdx.x] + s[t] - v;
        rowptr[i] = ex;
        cursor[i] = ex;
        dinv[i] = rsqrtf((float)(v + 1));   // +1 self-loop
    }
}

__global__ void k_fill(const int* __restrict__ ei, int* __restrict__ cursor,
                       const float* __restrict__ dinv, int2* __restrict__ csr, int E) {
    int e = blockIdx.x * blockDim.x + threadIdx.x;
    if (e >= E) return;
    int s = ei[e];
    int d = ei[E + e];
    int pos = atomicAdd(&cursor[d], 1);
    int2 p;
    p.x = s;
    p.y = __float_as_int(dinv[s] * dinv[d]);
    csr[pos] = p;
}

// ---- Y[N,128] = X[N,128] @ W[128,128].  BM=64, BK=32; 4x8 microtile. ----
__global__ __launch_bounds__(256) void k_gemm128(const float* __restrict__ X,
                                                 const float* __restrict__ W,
                                                 float* __restrict__ Y, int N) {
    __shared__ float sX[32][68];
    __shared__ float sW[32][128];
    const int tid = threadIdx.x;
    const int bm = blockIdx.x * 64;
    const int m0 = (tid >> 4) * 4;
    const int n0 = (tid & 15) * 8;
    const int xr = tid >> 3;
    const int xf = tid & 7;
    float acc[4][8] = {};
    for (int k0 = 0; k0 < 128; k0 += 32) {
        #pragma unroll
        for (int rr = 0; rr < 2; ++rr) {
            int row = bm + xr + rr * 32;
            int rc = min(row, N - 1);
            float4 v = *(const float4*)(X + (size_t)rc * 128 + k0 + xf * 4);
            int m = xr + rr * 32;
            sX[xf * 4 + 0][m] = v.x;
            sX[xf * 4 + 1][m] = v.y;
            sX[xf * 4 + 2][m] = v.z;
            sX[xf * 4 + 3][m] = v.w;
        }
        #pragma unroll
        for (int it = 0; it < 4; ++it) {
            int i = tid + it * 256;
            int wr = i >> 5;
            int wf = i & 31;
            *(float4*)(&sW[wr][wf * 4]) =
                *(const float4*)(W + (size_t)(k0 + wr) * 128 + wf * 4);
        }
        __syncthreads();
        #pragma unroll
        for (int kk = 0; kk < 32; ++kk) {
            float4 a  = *(const float4*)(&sX[kk][m0]);
            float4 b0 = *(const float4*)(&sW[kk][n0]);
            float4 b1 = *(const float4*)(&sW[kk][n0 + 4]);
            float av[4] = {a.x, a.y, a.z, a.w};
            float bv[8] = {b0.x, b0.y, b0.z, b0.w, b1.x, b1.y, b1.z, b1.w};
            #pragma unroll
            for (int r = 0; r < 4; ++r)
                #pragma unroll
                for (int c = 0; c < 8; ++c)
                    acc[r][c] = fmaf(av[r], bv[c], acc[r][c]);
        }
        __syncthreads();
    }
    #pragma unroll
    for (int r = 0; r < 4; ++r) {
        int row = bm + m0 + r;
        if (row < N) {
            float4 o0 = {acc[r][0], acc[r][1], acc[r][2], acc[r][3]};
            float4 o1 = {acc[r][4], acc[r][5], acc[r][6], acc[r][7]};
            *(float4*)(Y + (size_t)row * 128 + n0)     = o0;
            *(float4*)(Y + (size_t)row * 128 + n0 + 4) = o1;
        }
    }
}

// ---- Y[N,40] = X[N,128] @ W[128,40].  BM=128, BK=32; 4x5 microtile. ----
__global__ __launch_bounds__(256) void k_gemm40(const float* __restrict__ X,
                                                const float* __restrict__ W,
                                                float* __restrict__ Y, int N) {
    __shared__ float sX[32][132];
    __shared__ float sW[32][40];
    const int tid = threadIdx.x;
    const int bm = blockIdx.x * 128;
    const int m0 = (tid >> 3) * 4;
    const int n0 = (tid & 7) * 5;
    const int xf = tid & 7;
    float acc[4][5] = {};
    for (int k0 = 0; k0 < 128; k0 += 32) {
        #pragma unroll
        for (int it = 0; it < 4; ++it) {
            int i = tid + it * 256;
            int row = bm + (i >> 3);
            int rc = min(row, N - 1);
            float4 v = *(const float4*)(X + (size_t)rc * 128 + k0 + xf * 4);
            int m = i >> 3;
            sX[xf * 4 + 0][m] = v.x;
            sX[xf * 4 + 1][m] = v.y;
            sX[xf * 4 + 2][m] = v.z;
            sX[xf * 4 + 3][m] = v.w;
        }
        for (int i = tid; i < 320; i += 256) {
            int wr = i / 10;
            int wf = i - wr * 10;
            *(float4*)(&sW[wr][wf * 4]) =
                *(const float4*)(W + (size_t)(k0 + wr) * 40 + wf * 4);
        }
        __syncthreads();
        #pragma unroll
        for (int kk = 0; kk < 32; ++kk) {
            float4 a = *(const float4*)(&sX[kk][m0]);
            float av[4] = {a.x, a.y, a.z, a.w};
            #pragma unroll
            for (int c = 0; c < 5; ++c) {
                float b = sW[kk][n0 + c];
                #pragma unroll
                for (int r = 0; r < 4; ++r)
                    acc[r][c] = fmaf(av[r], b, acc[r][c]);
            }
        }
        __syncthreads();
    }
    #pragma unroll
    for (int r = 0; r < 4; ++r) {
        int row = bm + m0 + r;
        if (row < N) {
            #pragma unroll
            for (int c = 0; c < 5; ++c)
                Y[(size_t)row * 40 + n0 + c] = acc[r][c];
        }
    }
}

// One wave per dst node, F=128: lane holds float2.  Edge loop unrolled 8x:
// the 8 csr reads are independent, then 8 row-gathers are independent ->
// 8 loads in flight per wave instead of 1.  FMA order preserved.
template <bool RELU>
__global__ void k_agg128(const float* __restrict__ XW, const int* __restrict__ rowptr,
                         const int2* __restrict__ csr, const float* __restrict__ dinv,
                         const float* __restrict__ bias, float* __restrict__ out, int n) {
    int wave = threadIdx.x >> 6;
    int lane = threadIdx.x & 63;
    int d = blockIdx.x * 4 + wave;
    if (d >= n) return;
    const float2* xw2 = (const float2*)XW;
    float dv = dinv[d];
    float2 v = xw2[(size_t)d * 64 + lane];
    float2 acc;
    acc.x = dv * dv * v.x;
    acc.y = dv * dv * v.y;
    int beg = rowptr[d], end = rowptr[d + 1];
    int j = beg;
    for (; j + 8 <= end; j += 8) {
        int2 p0 = csr[j + 0], p1 = csr[j + 1], p2 = csr[j + 2], p3 = csr[j + 3];
        int2 p4 = csr[j + 4], p5 = csr[j + 5], p6 = csr[j + 6], p7 = csr[j + 7];
        float2 u0 = xw2[(size_t)p0.x * 64 + lane];
        float2 u1 = xw2[(size_t)p1.x * 64 + lane];
        float2 u2 = xw2[(size_t)p2.x * 64 + lane];
        float2 u3 = xw2[(size_t)p3.x * 64 + lane];
        float2 u4 = xw2[(size_t)p4.x * 64 + lane];
        float2 u5 = xw2[(size_t)p5.x * 64 + lane];
        float2 u6 = xw2[(size_t)p6.x * 64 + lane];
        float2 u7 = xw2[(size_t)p7.x * 64 + lane];
        acc.x = fmaf(__int_as_float(p0.y), u0.x, acc.x);
        acc.y = fmaf(__int_as_float(p0.y), u0.y, acc.y);
        acc.x = fmaf(__int_as_float(p1.y), u1.x, acc.x);
        acc.y = fmaf(__int_as_float(p1.y), u1.y, acc.y);
        acc.x = fmaf(__int_as_float(p2.y), u2.x, acc.x);
        acc.y = fmaf(__int_as_float(p2.y), u2.y, acc.y);
        acc.x = fmaf(__int_as_float(p3.y), u3.x, acc.x);
        acc.y = fmaf(__int_as_float(p3.y), u3.y, acc.y);
        acc.x = fmaf(__int_as_float(p4.y), u4.x, acc.x);
        acc.y = fmaf(__int_as_float(p4.y), u4.y, acc.y);
        acc.x = fmaf(__int_as_float(p5.y), u5.x, acc.x);
        acc.y = fmaf(__int_as_float(p5.y), u5.y, acc.y);
        acc.x = fmaf(__int_as_float(p6.y), u6.x, acc.x);
        acc.y = fmaf(__int_as_float(p6.y), u6.y, acc.y);
        acc.x = fmaf(__int_as_float(p7.y), u7.x, acc.x);
        acc.y = fmaf(__int_as_float(p7.y), u7.y, acc.y);
    }
    for (; j < end; ++j) {
        int2 p = csr[j];
        float w = __int_as_float(p.y);
        float2 u = xw2[(size_t)p.x * 64 + lane];
        acc.x = fmaf(w, u.x, acc.x);
        acc.y = fmaf(w, u.y, acc.y);
    }
    float2 b = ((const float2*)bias)[lane];
    acc.x += b.x;
    acc.y += b.y;
    if (RELU) {
        acc.x = fmaxf(acc.x, 0.f);
        acc.y = fmaxf(acc.y, 0.f);
    }
    ((float2*)out)[(size_t)d * 64 + lane] = acc;
}

__global__ void k_agg40(const float* __restrict__ XW, const int* __restrict__ rowptr,
                        const int2* __restrict__ csr, const float* __restrict__ dinv,
                        const float* __restrict__ bias, float* __restrict__ out, int n) {
    int wave = threadIdx.x >> 6;
    int lane = threadIdx.x & 63;
    int d = blockIdx.x * 4 + wave;
    if (d >= n || lane >= 40) return;
    float dv = dinv[d];
    float acc = dv * dv * XW[(size_t)d * 40 + lane];
    int beg = rowptr[d], end = rowptr[d + 1];
    int j = beg;
    for (; j + 4 <= end; j += 4) {
        int2 p0 = csr[j + 0], p1 = csr[j + 1], p2 = csr[j + 2], p3 = csr[j + 3];
        float u0 = XW[(size_t)p0.x * 40 + lane];
        float u1 = XW[(size_t)p1.x * 40 + lane];
        float u2 = XW[(size_t)p2.x * 40 + lane];
        float u3 = XW[(size_t)p3.x * 40 + lane];
        acc = fmaf(__int_as_float(p0.y), u0, acc);
        acc = fmaf(__int_as_float(p1.y), u1, acc);
        acc = fmaf(__int_as_float(p2.y), u2, acc);
        acc = fmaf(__int_as_float(p3.y), u3, acc);
    }
    for (; j < end; ++j) {
        int2 p = csr[j];
        acc = fmaf(__int_as_float(p.y), XW[(size_t)p.x * 40 + lane], acc);
    }
    out[(size_t)d * 40 + lane] = acc + bias[lane];
}

static inline int cdiv(long long a, int b) { return (int)((a + b - 1) / b); }

extern "C" void kernel_launch(void* const* d_in, const int* in_sizes, int n_in,
                              void* d_out, int out_size, void* d_ws, size_t ws_size,
                              hipStream_t stream) {
    const float* x  = (const float*)d_in[0];
    const int*   ei = (const int*)d_in[1];
    const float* W1 = (const float*)d_in[2];
    const float* b1 = (const float*)d_in[3];
    const float* W2 = (const float*)d_in[4];
    const float* b2 = (const float*)d_in[5];
    const float* W3 = (const float*)d_in[6];
    const float* b3 = (const float*)d_in[7];
    float* out = (float*)d_out;

    const int N = in_sizes[0] / 128;   // 50000
    const int E = in_sizes[1] / 2;     // 800000

    char* ws = (char*)d_ws;
    int*   deg    = (int*)ws;                 ws += (size_t)N * 4;
    int*   rowptr = (int*)ws;                 ws += (size_t)(N + 1) * 4;
    int*   cursor = (int*)ws;                 ws += (size_t)N * 4;
    float* dinv   = (float*)ws;               ws += (size_t)N * 4;
    int*   bsum   = (int*)ws;                 ws += (size_t)1024 * 4;
    ws = (char*)(((uintptr_t)ws + 15) & ~(uintptr_t)15);
    int2*  csr    = (int2*)ws;                ws += (size_t)E * 8;
    float* bufA   = (float*)ws;               ws += (size_t)N * 128 * 4;
    float* bufB   = (float*)ws;

    const int BT = 256;
    const int nb = cdiv(N, 256);

    // CSR build (per call; no state survives between calls)
    hipMemsetAsync(deg, 0, (size_t)N * 4, stream);
    k_deg_count<<<cdiv(E, BT), BT, 0, stream>>>(ei, deg, E);
    k_bsum<<<nb, 256, 0, stream>>>(deg, bsum, N);
    k_bscan<<<1, 1024, 0, stream>>>(bsum, rowptr + N, nb);
    k_rowptr<<<nb, 256, 0, stream>>>(deg, bsum, rowptr, cursor, dinv, N);
    k_fill<<<cdiv(E, BT), BT, 0, stream>>>(ei, cursor, dinv, csr, E);

    // layer 1
    k_gemm128<<<cdiv(N, 64), 256, 0, stream>>>(x, W1, bufA, N);
    k_agg128<true><<<cdiv(N, 4), BT, 0, stream>>>(bufA, rowptr, csr, dinv, b1, bufB, N);
    // layer 2
    k_gemm128<<<cdiv(N, 64), 256, 0, stream>>>(bufB, W2, bufA, N);
    k_agg128<true><<<cdiv(N, 4), BT, 0, stream>>>(bufA, rowptr, csr, dinv, b2, bufB, N);
    // layer 3
    k_gemm40<<<cdiv(N, 128), 256, 0, stream>>>(bufB, W3, bufA, N);
    k_agg40<<<cdiv(N, 4), BT, 0, stream>>>(bufA, rowptr, csr, dinv, b3, out, N);
}